// Round 1
// baseline (649.347 us; speedup 1.0000x reference)
//
#include <hip/hip_runtime.h>
#include <math.h>

#define NN 64
#define DD 128
#define PP 4800
#define KK 64
#define SLICES 25      // slices per sample
#define PSL 192        // positions per block (PP/SLICES)
#define PC 32          // positions per chunk
#define NCH 6          // chunks per block (PSL/PC)

#define XS_STRIDE 132  // pad D=128 -> 132 for bank spread
#define SA_STRIDE 68   // pad K=64  -> 68
#define CW_STRIDE 132

// workspace float offsets
#define AGG_SZ   (NN * KK * DD)   // 524288 floats (2 MB)
#define SSUM_SZ  (NN * KK)        // 4096 floats
#define INVN_SZ  (NN * PP)        // 307200 floats
#define AGG_OFF  0
#define SSUM_OFF (AGG_SZ)
#define INVN_OFF (AGG_SZ + SSUM_SZ)

union F4 { float4 v; float f[4]; };

// ---------------------------------------------------------------------------
// Pass 1: per-(n,p) inverse L2 norm over channel dim D.
// Lanes are consecutive p -> coalesced row reads.
// ---------------------------------------------------------------------------
__global__ __launch_bounds__(256) void prepass_kernel(const float* __restrict__ x,
                                                      float* __restrict__ invn) {
  int idx = blockIdx.x * 256 + threadIdx.x;   // 0 .. N*P-1 exactly
  int n = idx / PP, p = idx % PP;
  const float* xp = x + (size_t)n * DD * PP + p;
  float s = 0.f;
#pragma unroll 8
  for (int d = 0; d < DD; ++d) {
    float v = xp[(size_t)d * PP];
    s = fmaf(v, v, s);
  }
  invn[idx] = 1.0f / fmaxf(sqrtf(s), 1e-12f);
}

// ---------------------------------------------------------------------------
// Pass 2: fused normalize -> 1x1 conv (logits) -> softmax over K -> agg/ssum.
// One block = (n, slice of 192 positions), 6 chunks of 32 positions in LDS.
// agg accumulated in registers across chunks, one atomic pass per block.
// ---------------------------------------------------------------------------
__global__ __launch_bounds__(256) void main_kernel(const float* __restrict__ x,
                                                   const float* __restrict__ conv_w,
                                                   const float* __restrict__ invn,
                                                   float* __restrict__ agg,
                                                   float* __restrict__ ssum) {
  __shared__ float xs[PC][XS_STRIDE];   // 16896 B, xs[p][d] = normalized x
  __shared__ float sa[PC][SA_STRIDE];   //  8704 B, sa[p][k] = logits -> softmax
  __shared__ float cw[KK][CW_STRIDE];   // 33792 B, cw[k][d]

  const int b = blockIdx.x;
  const int n = b / SLICES;
  const int sl = b % SLICES;
  const int pbase = sl * PSL;
  const int t = threadIdx.x;

  // stage conv_w: coalesced global read, conflict-free LDS write
#pragma unroll
  for (int it = 0; it < (KK * DD) / 256; ++it) {   // 32 iters
    int idx = t + 256 * it;
    int k = idx >> 7, d = idx & 127;
    cw[k][d] = conv_w[idx];
  }

  // agg register tile: k in [k0,k0+4), d in [d0,d0+8)  (64k x 128d over 256 thr)
  const int k0 = (t >> 4) * 4;
  const int d0 = (t & 15) * 8;
  // logits tile: p in {pq, pq+16}, k in [k0,k0+4)
  const int pq = t & 15;

  float agga[4][8];
#pragma unroll
  for (int i = 0; i < 4; ++i)
#pragma unroll
    for (int j = 0; j < 8; ++j) agga[i][j] = 0.f;
  float ssacc = 0.f;

  for (int c = 0; c < NCH; ++c) {
    const int p0 = pbase + c * PC;
    __syncthreads();  // xs/sa free from previous chunk (and cw ready on c==0)

    // ---- stage normalized x chunk: xs[p][d] = x[n,d,p0+p] * invn[n,p0+p]
#pragma unroll
    for (int it = 0; it < 4; ++it) {
      int idx = t + 256 * it;            // 0..1023 over (d, p/4)
      int d = idx >> 3, p4 = idx & 7;
      const float4 xv = *(const float4*)(x + ((size_t)n * DD + d) * PP + p0 + 4 * p4);
      const float4 iv = *(const float4*)(invn + (size_t)n * PP + p0 + 4 * p4);
      int pr = 4 * p4;
      xs[pr + 0][d] = xv.x * iv.x;
      xs[pr + 1][d] = xv.y * iv.y;
      xs[pr + 2][d] = xv.z * iv.z;
      xs[pr + 3][d] = xv.w * iv.w;
    }
    __syncthreads();

    // ---- logits: sa[p][k] = sum_d cw[k][d] * xs[p][d]
    {
      float acc[2][4] = {{0.f, 0.f, 0.f, 0.f}, {0.f, 0.f, 0.f, 0.f}};
#pragma unroll 2
      for (int d = 0; d < DD; d += 4) {
        F4 xa, xb, c0, c1, c2, c3;
        xa.v = *(const float4*)&xs[pq][d];
        xb.v = *(const float4*)&xs[pq + 16][d];
        c0.v = *(const float4*)&cw[k0 + 0][d];
        c1.v = *(const float4*)&cw[k0 + 1][d];
        c2.v = *(const float4*)&cw[k0 + 2][d];
        c3.v = *(const float4*)&cw[k0 + 3][d];
#pragma unroll
        for (int di = 0; di < 4; ++di) {
          acc[0][0] = fmaf(xa.f[di], c0.f[di], acc[0][0]);
          acc[0][1] = fmaf(xa.f[di], c1.f[di], acc[0][1]);
          acc[0][2] = fmaf(xa.f[di], c2.f[di], acc[0][2]);
          acc[0][3] = fmaf(xa.f[di], c3.f[di], acc[0][3]);
          acc[1][0] = fmaf(xb.f[di], c0.f[di], acc[1][0]);
          acc[1][1] = fmaf(xb.f[di], c1.f[di], acc[1][1]);
          acc[1][2] = fmaf(xb.f[di], c2.f[di], acc[1][2]);
          acc[1][3] = fmaf(xb.f[di], c3.f[di], acc[1][3]);
        }
      }
      F4 o0, o1;
#pragma unroll
      for (int ki = 0; ki < 4; ++ki) { o0.f[ki] = acc[0][ki]; o1.f[ki] = acc[1][ki]; }
      *(float4*)&sa[pq][k0] = o0.v;
      *(float4*)&sa[pq + 16][k0] = o1.v;
    }
    __syncthreads();

    // ---- softmax over k (K=64) per position: 8 lanes x 8 values each
    {
      int pp = t >> 3, j = t & 7;
      F4 e0, e1;
      e0.v = *(const float4*)&sa[pp][8 * j];
      e1.v = *(const float4*)&sa[pp][8 * j + 4];
      float m = e0.f[0];
#pragma unroll
      for (int i = 1; i < 4; ++i) m = fmaxf(m, e0.f[i]);
#pragma unroll
      for (int i = 0; i < 4; ++i) m = fmaxf(m, e1.f[i]);
      m = fmaxf(m, __shfl_xor(m, 1));
      m = fmaxf(m, __shfl_xor(m, 2));
      m = fmaxf(m, __shfl_xor(m, 4));
      float s = 0.f;
#pragma unroll
      for (int i = 0; i < 4; ++i) { e0.f[i] = __expf(e0.f[i] - m); s += e0.f[i]; }
#pragma unroll
      for (int i = 0; i < 4; ++i) { e1.f[i] = __expf(e1.f[i] - m); s += e1.f[i]; }
      s += __shfl_xor(s, 1);
      s += __shfl_xor(s, 2);
      s += __shfl_xor(s, 4);
      float inv = 1.0f / s;  // s >= 1 (max term) -> safe
#pragma unroll
      for (int i = 0; i < 4; ++i) { e0.f[i] *= inv; e1.f[i] *= inv; }
      *(float4*)&sa[pp][8 * j] = e0.v;
      *(float4*)&sa[pp][8 * j + 4] = e1.v;
    }
    __syncthreads();

    // ---- ssum partial: k = t&63, 8 positions per wave
    {
      int k = t & 63, pr = (t >> 6) * 8;
#pragma unroll
      for (int i = 0; i < 8; ++i) ssacc += sa[pr + i][k];
    }

    // ---- agg: agga[ki][di] += sum_p sa[p][k0+ki] * xs[p][d0+di]
#pragma unroll 4
    for (int p = 0; p < PC; ++p) {
      F4 s4, xA, xB;
      s4.v = *(const float4*)&sa[p][k0];
      xA.v = *(const float4*)&xs[p][d0];
      xB.v = *(const float4*)&xs[p][d0 + 4];
#pragma unroll
      for (int ki = 0; ki < 4; ++ki) {
        float sv = s4.f[ki];
#pragma unroll
        for (int di = 0; di < 4; ++di) {
          agga[ki][di]     = fmaf(sv, xA.f[di], agga[ki][di]);
          agga[ki][di + 4] = fmaf(sv, xB.f[di], agga[ki][di + 4]);
        }
      }
    }
  }

  // ---- flush block partials (25 slices per n race via atomics; ws zeroed)
#pragma unroll
  for (int ki = 0; ki < 4; ++ki)
#pragma unroll
    for (int di = 0; di < 8; ++di)
      atomicAdd(&agg[((size_t)n * KK + (k0 + ki)) * DD + d0 + di], agga[ki][di]);
  atomicAdd(&ssum[n * KK + (t & 63)], ssacc);
}

// ---------------------------------------------------------------------------
// Pass 3: vlad = agg - ssum*centroids; intra-norm over d; global norm; store.
// One block per n; thread = (k = t>>2, quarter j = t&3) owns 32 d's.
// ---------------------------------------------------------------------------
__global__ __launch_bounds__(256) void epilogue_kernel(const float* __restrict__ agg,
                                                       const float* __restrict__ ssum,
                                                       const float* __restrict__ cent,
                                                       float* __restrict__ out) {
  __shared__ float wsum[4];
  const int n = blockIdx.x, t = threadIdx.x;
  const int k = t >> 2, j = t & 3;
  const float* ap = agg + ((size_t)n * KK + k) * DD + 32 * j;
  const float* cp = cent + (size_t)k * DD + 32 * j;
  const float sk = ssum[n * KK + k];

  float v[32];
  float ss = 0.f;
#pragma unroll
  for (int i = 0; i < 32; i += 4) {
    float4 a4 = *(const float4*)(ap + i);
    float4 c4 = *(const float4*)(cp + i);
    v[i + 0] = fmaf(-sk, c4.x, a4.x);
    v[i + 1] = fmaf(-sk, c4.y, a4.y);
    v[i + 2] = fmaf(-sk, c4.z, a4.z);
    v[i + 3] = fmaf(-sk, c4.w, a4.w);
    ss = fmaf(v[i + 0], v[i + 0], ss);
    ss = fmaf(v[i + 1], v[i + 1], ss);
    ss = fmaf(v[i + 2], v[i + 2], ss);
    ss = fmaf(v[i + 3], v[i + 3], ss);
  }
  // intra-normalization: combine the 4 threads of this k
  ss += __shfl_xor(ss, 1);
  ss += __shfl_xor(ss, 2);
  float rinv = 1.0f / fmaxf(sqrtf(ss), 1e-12f);

  float gp = 0.f;
#pragma unroll
  for (int i = 0; i < 32; ++i) { v[i] *= rinv; gp = fmaf(v[i], v[i], gp); }

  // global L2 over all K*D: wave butterfly + cross-wave via LDS
#pragma unroll
  for (int off = 1; off < 64; off <<= 1) gp += __shfl_xor(gp, off);
  if ((t & 63) == 0) wsum[t >> 6] = gp;
  __syncthreads();
  float g = wsum[0] + wsum[1] + wsum[2] + wsum[3];
  float ginv = 1.0f / fmaxf(sqrtf(g), 1e-12f);

  float* op = out + (size_t)n * KK * DD + (size_t)k * DD + 32 * j;
#pragma unroll
  for (int i = 0; i < 32; i += 4) {
    float4 o;
    o.x = v[i + 0] * ginv;
    o.y = v[i + 1] * ginv;
    o.z = v[i + 2] * ginv;
    o.w = v[i + 3] * ginv;
    *(float4*)(op + i) = o;
  }
}

extern "C" void kernel_launch(void* const* d_in, const int* in_sizes, int n_in,
                              void* d_out, int out_size, void* d_ws, size_t ws_size,
                              hipStream_t stream) {
  const float* x      = (const float*)d_in[0];
  const float* conv_w = (const float*)d_in[1];
  const float* cent   = (const float*)d_in[2];
  float* out = (float*)d_out;
  float* ws  = (float*)d_ws;

  float* agg  = ws + AGG_OFF;
  float* ssum = ws + SSUM_OFF;
  float* invn = ws + INVN_OFF;

  // zero the atomic accumulators (ws is re-poisoned to 0xAA before each launch)
  hipMemsetAsync(agg, 0, (size_t)(AGG_SZ + SSUM_SZ) * sizeof(float), stream);

  prepass_kernel<<<(NN * PP) / 256, 256, 0, stream>>>(x, invn);
  main_kernel<<<NN * SLICES, 256, 0, stream>>>(x, conv_w, invn, agg, ssum);
  epilogue_kernel<<<NN, 256, 0, stream>>>(agg, ssum, cent, out);
}

// Round 2
// 277.120 us; speedup vs baseline: 2.3432x; 2.3432x over previous
//
#include <hip/hip_runtime.h>
#include <math.h>

#define NN 64
#define DD 128
#define PP 4800
#define KK 64
#define BPN 15          // blocks per sample n
#define PB  320         // positions per block (BPN*PB == PP)
#define CP  64          // positions per chunk
#define NCH 5           // chunks per block (PB/CP)

#define WT  136         // w_s   row stride (bf16 elems): 64 k rows x 128 d (+8 pad)
#define XPT 136         // xpd   row stride: 64 p rows x 128 d (+8 pad)
#define XDT 88          // xdp   row stride: 128 d rows x 64 p (+24 pad... 88 for b128 bank spread)
#define SAT 88          // sa_s  row stride: 64 k rows x 64 p (+24 pad)

typedef __attribute__((ext_vector_type(8))) short bf16x8;
typedef __attribute__((ext_vector_type(4))) float f32x4;

__device__ __forceinline__ unsigned short f2bf(float f) {
  unsigned u = __float_as_uint(f);
  u += 0x7fffu + ((u >> 16) & 1u);          // RNE
  return (unsigned short)(u >> 16);
}
__device__ __forceinline__ float bf2f(unsigned short s) {
  return __uint_as_float(((unsigned)s) << 16);
}

// ---------------------------------------------------------------------------
// Fused main kernel: stage x chunk (bf16, two layouts) -> per-p inv-norm ->
// GEMM1 (logits, MFMA) -> in-register softmax over K -> GEMM2 (agg, MFMA,
// accumulated in C-regs across chunks) -> one flush per block.
// Normalization folded: logits *= invn[p] before softmax; sa *= invn[p]
// before GEMM2, so both GEMMs consume UNNORMALIZED bf16 x.
// ---------------------------------------------------------------------------
template <bool ATOMIC>
__global__ __launch_bounds__(256, 2) void main_kernel(const float* __restrict__ x,
                                                      const float* __restrict__ conv_w,
                                                      float* __restrict__ pagg,
                                                      float* __restrict__ pssum) {
  __shared__ __align__(16) unsigned short w_s[KK * WT];    // 17408 B
  __shared__ __align__(16) unsigned short xpd[CP * XPT];   // 17408 B  x[p][d]
  __shared__ __align__(16) unsigned short xdp[DD * XDT];   // 22528 B  x[d][p]
  __shared__ __align__(16) unsigned short sa_s[KK * SAT];  // 11264 B  sa[k][p]
  __shared__ float invn_s[CP];                             //   256 B
  __shared__ float ssred[256];                             //  1024 B

  const int b = blockIdx.x;
  const int n = b / BPN;
  const int sl = b % BPN;
  const int t = threadIdx.x;
  const int lane = t & 63;
  const int wv = t >> 6;        // wave 0..3
  const int lq = lane >> 4;     // quad 0..3
  const int ll = lane & 15;

  // ---- stage conv_w -> bf16 LDS (once per block)
  {
    int k = t >> 2, h = t & 3;  // 32 floats per thread
    const float4* wp = (const float4*)(conv_w + k * DD + h * 32);
    unsigned short* dst = &w_s[k * WT + h * 32];
#pragma unroll
    for (int i = 0; i < 4; ++i) {
      float4 a = wp[2 * i], c = wp[2 * i + 1];
      bf16x8 o = {(short)f2bf(a.x), (short)f2bf(a.y), (short)f2bf(a.z), (short)f2bf(a.w),
                  (short)f2bf(c.x), (short)f2bf(c.y), (short)f2bf(c.z), (short)f2bf(c.w)};
      *(bf16x8*)&dst[8 * i] = o;
    }
  }

  f32x4 acc[8];                 // GEMM2 accum: k-tile = wv, 8 d-tiles
#pragma unroll
  for (int i = 0; i < 8; ++i) acc[i] = (f32x4){0.f, 0.f, 0.f, 0.f};
  float ssacc[16];
#pragma unroll
  for (int i = 0; i < 16; ++i) ssacc[i] = 0.f;

  for (int c = 0; c < NCH; ++c) {
    const int p0 = sl * PB + c * CP;
    __syncthreads();  // xs/sa free from previous chunk; w_s staged (c==0)

    // ---- stage x chunk: bf16 in both [d][p] and [p][d] layouts
    {
      int d = t >> 1, h = t & 1;  // 32 p's per thread along one d-row
      const float4* xp = (const float4*)(x + ((size_t)n * DD + d) * PP + p0 + h * 32);
      unsigned short* xdrow = &xdp[d * XDT + h * 32];
#pragma unroll
      for (int i = 0; i < 4; ++i) {
        float4 a = xp[2 * i], c2 = xp[2 * i + 1];
        unsigned short e0 = f2bf(a.x), e1 = f2bf(a.y), e2 = f2bf(a.z), e3 = f2bf(a.w);
        unsigned short e4 = f2bf(c2.x), e5 = f2bf(c2.y), e6 = f2bf(c2.z), e7 = f2bf(c2.w);
        bf16x8 o = {(short)e0, (short)e1, (short)e2, (short)e3,
                    (short)e4, (short)e5, (short)e6, (short)e7};
        *(bf16x8*)&xdrow[8 * i] = o;
        int pl = h * 32 + 8 * i;
        xpd[(pl + 0) * XPT + d] = e0;
        xpd[(pl + 1) * XPT + d] = e1;
        xpd[(pl + 2) * XPT + d] = e2;
        xpd[(pl + 3) * XPT + d] = e3;
        xpd[(pl + 4) * XPT + d] = e4;
        xpd[(pl + 5) * XPT + d] = e5;
        xpd[(pl + 6) * XPT + d] = e6;
        xpd[(pl + 7) * XPT + d] = e7;
      }
    }
    __syncthreads();

    // ---- per-p inverse L2 norm (from bf16 copy; rel err ~1e-4, negligible)
    if (t < 128) {
      int p = t >> 1, hh = t & 1;
      const unsigned short* row = &xpd[p * XPT + hh * 64];
      float s = 0.f;
#pragma unroll
      for (int i = 0; i < 8; ++i) {
        bf16x8 v = *(const bf16x8*)&row[8 * i];
#pragma unroll
        for (int j = 0; j < 8; ++j) {
          float f = bf2f((unsigned short)v[j]);
          s = fmaf(f, f, s);
        }
      }
      s += __shfl_xor(s, 1);
      if (hh == 0) invn_s[p] = 1.0f / fmaxf(sqrtf(s), 1e-12f);
    }
    __syncthreads();

    // ---- GEMM1: logits[k][p] for p-tile = wv; all 4 k-tiles in this wave
    {
      f32x4 lg[4];
#pragma unroll
      for (int kt = 0; kt < 4; ++kt) lg[kt] = (f32x4){0.f, 0.f, 0.f, 0.f};
#pragma unroll
      for (int ks = 0; ks < 4; ++ks) {
        bf16x8 bfrag = *(const bf16x8*)&xpd[(wv * 16 + ll) * XPT + ks * 32 + lq * 8];
#pragma unroll
        for (int kt = 0; kt < 4; ++kt) {
          bf16x8 afrag = *(const bf16x8*)&w_s[(kt * 16 + ll) * WT + ks * 32 + lq * 8];
          lg[kt] = __builtin_amdgcn_mfma_f32_16x16x32_bf16(afrag, bfrag, lg[kt], 0, 0, 0);
        }
      }
      // ---- softmax over K=64: lane holds k = kt*16 + lq*4 + r for p = wv*16+ll
      float iv = invn_s[wv * 16 + ll];
      float vals[16];
      float m = -1e30f;
#pragma unroll
      for (int kt = 0; kt < 4; ++kt)
#pragma unroll
        for (int r = 0; r < 4; ++r) {
          float v = lg[kt][r] * iv;
          vals[kt * 4 + r] = v;
          m = fmaxf(m, v);
        }
      m = fmaxf(m, __shfl_xor(m, 16));
      m = fmaxf(m, __shfl_xor(m, 32));
      float se = 0.f;
#pragma unroll
      for (int i = 0; i < 16; ++i) {
        float e = __expf(vals[i] - m);
        vals[i] = e;
        se += e;
      }
      se += __shfl_xor(se, 16);
      se += __shfl_xor(se, 32);
      float rinv = 1.0f / se;
      float r2 = rinv * iv;  // fold invn into sa for GEMM2
#pragma unroll
      for (int kt = 0; kt < 4; ++kt)
#pragma unroll
        for (int r = 0; r < 4; ++r) {
          float e = vals[kt * 4 + r];
          ssacc[kt * 4 + r] += e * rinv;  // true sa for ssum
          sa_s[(kt * 16 + lq * 4 + r) * SAT + wv * 16 + ll] = f2bf(e * r2);
        }
    }
    __syncthreads();

    // ---- GEMM2: acc[k-tile=wv][d-tile dt] += SA * X^T over this chunk's p
#pragma unroll
    for (int ks = 0; ks < 2; ++ks) {
      bf16x8 afrag = *(const bf16x8*)&sa_s[(wv * 16 + ll) * SAT + ks * 32 + lq * 8];
#pragma unroll
      for (int dt = 0; dt < 8; ++dt) {
        bf16x8 bfrag = *(const bf16x8*)&xdp[(dt * 16 + ll) * XDT + ks * 32 + lq * 8];
        acc[dt] = __builtin_amdgcn_mfma_f32_16x16x32_bf16(afrag, bfrag, acc[dt], 0, 0, 0);
      }
    }
  }

  // ---- flush agg: lane holds agg[k = 16wv + 4lq + r][d = 16dt + ll]
  {
    size_t base = ATOMIC ? (size_t)n * (KK * DD) : (size_t)(n * BPN + sl) * (KK * DD);
#pragma unroll
    for (int dt = 0; dt < 8; ++dt)
#pragma unroll
      for (int r = 0; r < 4; ++r) {
        int off = (16 * wv + 4 * lq + r) * DD + dt * 16 + ll;
        if (ATOMIC)
          atomicAdd(&pagg[base + off], acc[dt][r]);
        else
          pagg[base + off] = acc[dt][r];
      }
  }
  // ---- flush ssum: reduce over the 16 p-lanes, combine 4 waves via LDS
#pragma unroll
  for (int i = 0; i < 16; ++i) {
    float s = ssacc[i];
    s += __shfl_xor(s, 1);
    s += __shfl_xor(s, 2);
    s += __shfl_xor(s, 4);
    s += __shfl_xor(s, 8);
    if (ll == 0) ssred[wv * 64 + (i >> 2) * 16 + lq * 4 + (i & 3)] = s;
  }
  __syncthreads();
  if (t < 64) {
    float s = ssred[t] + ssred[64 + t] + ssred[128 + t] + ssred[192 + t];
    if (ATOMIC)
      atomicAdd(&pssum[n * KK + t], s);
    else
      pssum[(n * BPN + sl) * KK + t] = s;
  }
}

// ---------------------------------------------------------------------------
// Epilogue: reduce partial slabs -> vlad = agg - ssum*cent -> intra-norm ->
// global norm -> store. One block per n.
// ---------------------------------------------------------------------------
__global__ __launch_bounds__(256) void epilogue_kernel(const float* __restrict__ pagg,
                                                       const float* __restrict__ pssum,
                                                       const float* __restrict__ cent,
                                                       float* __restrict__ out, int S) {
  __shared__ __align__(16) float agg_s[KK * 132];  // 33792 B (padded stride)
  __shared__ float sred[KK];
  __shared__ float wsum[4];
  const int n = blockIdx.x, t = threadIdx.x;

  // phase 1: sum S slabs into LDS (coalesced float4)
#pragma unroll
  for (int it = 0; it < 8; ++it) {
    int idx = t + 256 * it;  // float4 index 0..2047
    float4 a = {0.f, 0.f, 0.f, 0.f};
    for (int s = 0; s < S; ++s) {
      float4 v = ((const float4*)(pagg + (size_t)(n * S + s) * (KK * DD)))[idx];
      a.x += v.x; a.y += v.y; a.z += v.z; a.w += v.w;
    }
    int row = idx >> 5, col = (idx & 31) * 4;
    *(float4*)&agg_s[row * 132 + col] = a;
  }
  if (t < KK) {
    float s = 0.f;
    for (int ss = 0; ss < S; ++ss) s += pssum[(n * S + ss) * KK + t];
    sred[t] = s;
  }
  __syncthreads();

  // phase 2
  const int k = t >> 2, j = t & 3;
  const float* ap = &agg_s[k * 132 + 32 * j];
  const float* cp = cent + (size_t)k * DD + 32 * j;
  const float sk = sred[k];

  float v[32];
  float ss = 0.f;
#pragma unroll
  for (int i = 0; i < 32; i += 4) {
    float4 a4 = *(const float4*)(ap + i);
    float4 c4 = *(const float4*)(cp + i);
    v[i + 0] = fmaf(-sk, c4.x, a4.x);
    v[i + 1] = fmaf(-sk, c4.y, a4.y);
    v[i + 2] = fmaf(-sk, c4.z, a4.z);
    v[i + 3] = fmaf(-sk, c4.w, a4.w);
    ss = fmaf(v[i + 0], v[i + 0], ss);
    ss = fmaf(v[i + 1], v[i + 1], ss);
    ss = fmaf(v[i + 2], v[i + 2], ss);
    ss = fmaf(v[i + 3], v[i + 3], ss);
  }
  ss += __shfl_xor(ss, 1);
  ss += __shfl_xor(ss, 2);
  float rinv = 1.0f / fmaxf(sqrtf(ss), 1e-12f);

  float gp = 0.f;
#pragma unroll
  for (int i = 0; i < 32; ++i) {
    v[i] *= rinv;
    gp = fmaf(v[i], v[i], gp);
  }
#pragma unroll
  for (int off = 1; off < 64; off <<= 1) gp += __shfl_xor(gp, off);
  if ((t & 63) == 0) wsum[t >> 6] = gp;
  __syncthreads();
  float g = wsum[0] + wsum[1] + wsum[2] + wsum[3];
  float ginv = 1.0f / fmaxf(sqrtf(g), 1e-12f);

  float* op = out + (size_t)n * KK * DD + (size_t)k * DD + 32 * j;
#pragma unroll
  for (int i = 0; i < 32; i += 4) {
    float4 o;
    o.x = v[i + 0] * ginv;
    o.y = v[i + 1] * ginv;
    o.z = v[i + 2] * ginv;
    o.w = v[i + 3] * ginv;
    *(float4*)(op + i) = o;
  }
}

extern "C" void kernel_launch(void* const* d_in, const int* in_sizes, int n_in,
                              void* d_out, int out_size, void* d_ws, size_t ws_size,
                              hipStream_t stream) {
  const float* x      = (const float*)d_in[0];
  const float* conv_w = (const float*)d_in[1];
  const float* cent   = (const float*)d_in[2];
  float* out = (float*)d_out;
  float* ws  = (float*)d_ws;

  const size_t need_partial =
      ((size_t)NN * BPN * KK * DD + (size_t)NN * BPN * KK) * sizeof(float);

  if (ws_size >= need_partial) {
    // partial-slab path: each block writes its own slab, no atomics, no memset
    float* pagg  = ws;
    float* pssum = ws + (size_t)NN * BPN * KK * DD;
    main_kernel<false><<<NN * BPN, 256, 0, stream>>>(x, conv_w, pagg, pssum);
    epilogue_kernel<<<NN, 256, 0, stream>>>(pagg, pssum, cent, out, BPN);
  } else {
    // atomic fallback into a single slab per n
    float* pagg  = ws;
    float* pssum = ws + (size_t)NN * KK * DD;
    hipMemsetAsync(ws, 0, ((size_t)NN * KK * DD + (size_t)NN * KK) * sizeof(float), stream);
    main_kernel<true><<<NN * BPN, 256, 0, stream>>>(x, conv_w, pagg, pssum);
    epilogue_kernel<<<NN, 256, 0, stream>>>(pagg, pssum, cent, out, 1);
  }
}

// Round 3
// 246.810 us; speedup vs baseline: 2.6310x; 1.1228x over previous
//
#include <hip/hip_runtime.h>
#include <hip/hip_bf16.h>
#include <math.h>

#define NN 64
#define DD 128
#define PP 4800
#define KK 64
#define BPN 15          // blocks per sample n
#define PB  320         // positions per block
#define CP  64          // positions per chunk
#define NCH 5           // chunks per block

#define WT  136         // w_s  row stride (halfwords): mult of 8
#define XPT 136         // xpd  row stride (halfwords): mult of 8, chunk-swizzled columns
#define XDT 72          // xdp  row stride
#define SAT 72          // sa_s row stride

// ws float offsets
#define PAGG_SZ  ((size_t)NN * BPN * KK * DD)   // 31.46 MB
#define PSSUM_SZ ((size_t)NN * BPN * KK)
#define VTMP_SZ  ((size_t)NN * KK * DD)
#define GSUM_SZ  ((size_t)NN * 8)

typedef __attribute__((ext_vector_type(8))) short bf16x8;
typedef __attribute__((ext_vector_type(4))) float f32x4;

__device__ __forceinline__ unsigned short f2bf(float f) {
  unsigned u = __float_as_uint(f);
  u += 0x7fffu + ((u >> 16) & 1u);  // RNE
  return (unsigned short)(u >> 16);
}
__device__ __forceinline__ unsigned pk2(float a, float b) {
  union { __hip_bfloat162 h2; unsigned u; } cv;
  cv.h2 = __float22bfloat162_rn(make_float2(a, b));  // low = a, high = b
  return cv.u;
}

// ---------------------------------------------------------------------------
// Fused main: reg-prefetched staging (fp32 -> bf16, [d][p] + swizzled [p][d]),
// fp32 per-p ssq fused into staging, MFMA GEMM1 -> softmax -> MFMA GEMM2,
// 3 barriers per chunk, one partial-slab flush per block (no atomics).
// ---------------------------------------------------------------------------
__global__ __launch_bounds__(256, 2) void main_kernel(const float* __restrict__ x,
                                                      const float* __restrict__ conv_w,
                                                      float* __restrict__ pagg,
                                                      float* __restrict__ pssum) {
  __shared__ __align__(16) unsigned short w_s[KK * WT];    // 17408 B
  __shared__ __align__(16) unsigned short xpd[CP * XPT];   // 17408 B (col-swizzled)
  __shared__ __align__(16) unsigned short xdp[DD * XDT];   // 18432 B
  __shared__ __align__(16) unsigned short sa_s[KK * SAT];  //  9216 B
  __shared__ float red_s[256];  // [0,64): per-p ssq accumulator; flush: 256 partials

  const int b = blockIdx.x;
  const int n = b / BPN, sl = b % BPN;
  const int t = threadIdx.x, lane = t & 63, wv = t >> 6;
  const int lq = lane >> 4, ll = lane & 15;
  const int pb = t & 7, db = t >> 3;  // staging tile: p in [8pb,8pb+8), d in [4db,4db+4)

  // ---- stage conv_w -> bf16 LDS (once)
  {
    int k = t >> 2, h = t & 3;
    const float* wp = conv_w + k * DD + h * 32;
    unsigned short* dst = &w_s[k * WT + h * 32];
#pragma unroll
    for (int i = 0; i < 4; ++i) {
      float4 a = *(const float4*)(wp + 8 * i);
      float4 c = *(const float4*)(wp + 8 * i + 4);
      uint4 o = {pk2(a.x, a.y), pk2(a.z, a.w), pk2(c.x, c.y), pk2(c.z, c.w)};
      *(uint4*)&dst[8 * i] = o;
    }
  }
  if (t < 64) red_s[t] = 0.f;

  const float* xb = x + (size_t)n * DD * PP + (size_t)(4 * db) * PP + sl * PB + 8 * pb;

  float4 pf[8];
#pragma unroll
  for (int r = 0; r < 4; ++r) {
    pf[2 * r]     = *(const float4*)(xb + (size_t)r * PP);
    pf[2 * r + 1] = *(const float4*)(xb + (size_t)r * PP + 4);
  }

  f32x4 acc[8];
#pragma unroll
  for (int i = 0; i < 8; ++i) acc[i] = (f32x4){0.f, 0.f, 0.f, 0.f};
  float ssacc[16];
#pragma unroll
  for (int i = 0; i < 16; ++i) ssacc[i] = 0.f;

  for (int c = 0; c < NCH; ++c) {
    float4 cur[8];
#pragma unroll
    for (int i = 0; i < 8; ++i) cur[i] = pf[i];
    if (c + 1 < NCH) {  // prefetch next chunk; completes during this chunk's compute
      const float* xc = xb + (c + 1) * CP;
#pragma unroll
      for (int r = 0; r < 4; ++r) {
        pf[2 * r]     = *(const float4*)(xc + (size_t)r * PP);
        pf[2 * r + 1] = *(const float4*)(xc + (size_t)r * PP + 4);
      }
    }

    // ---- fp32 per-p partial sum-of-squares over this thread's 4 d-rows
    float sq[8];
#pragma unroll
    for (int h = 0; h < 2; ++h)
#pragma unroll
      for (int j = 0; j < 4; ++j) {
        float s = 0.f;
#pragma unroll
        for (int r = 0; r < 4; ++r) {
          float v = (&cur[2 * r + h].x)[j];
          s = fmaf(v, v, s);
        }
        sq[4 * h + j] = s;
      }
#pragma unroll
    for (int i = 0; i < 8; ++i) {  // reduce over the wave's 8 db values
      sq[i] += __shfl_xor(sq[i], 8);
      sq[i] += __shfl_xor(sq[i], 16);
      sq[i] += __shfl_xor(sq[i], 32);
    }

    __syncthreads();  // xpd/xdp/sa_s free (prev GEMM2 done), red_s[0:64) zeroed

    if (lane < 8) {  // one lane per p-block per wave adds its wave's partial
#pragma unroll
      for (int j = 0; j < 8; ++j) atomicAdd(&red_s[8 * lane + j], sq[j]);
    }

    // ---- convert + stage: xdp b128 rows, xpd transposed b64 (chunk-swizzled)
    {
      unsigned prow[4][4];
#pragma unroll
      for (int r = 0; r < 4; ++r) {
        const float4& a = cur[2 * r];
        const float4& c2 = cur[2 * r + 1];
        prow[r][0] = pk2(a.x, a.y);
        prow[r][1] = pk2(a.z, a.w);
        prow[r][2] = pk2(c2.x, c2.y);
        prow[r][3] = pk2(c2.z, c2.w);
        uint4 o = {prow[r][0], prow[r][1], prow[r][2], prow[r][3]};
        *(uint4*)&xdp[(4 * db + r) * XDT + 8 * pb] = o;
      }
      const int colh = (((db >> 1) ^ pb) << 3) + (db & 1) * 4;  // swizzled column
#pragma unroll
      for (int j2 = 0; j2 < 4; ++j2) {
        unsigned lo01 = __builtin_amdgcn_perm(prow[1][j2], prow[0][j2], 0x05040100u);
        unsigned hi01 = __builtin_amdgcn_perm(prow[1][j2], prow[0][j2], 0x07060302u);
        unsigned lo23 = __builtin_amdgcn_perm(prow[3][j2], prow[2][j2], 0x05040100u);
        unsigned hi23 = __builtin_amdgcn_perm(prow[3][j2], prow[2][j2], 0x07060302u);
        int p_e = 8 * pb + 2 * j2;
        *(uint2*)&xpd[p_e * XPT + colh]       = make_uint2(lo01, lo23);
        *(uint2*)&xpd[(p_e + 1) * XPT + colh] = make_uint2(hi01, hi23);
      }
    }
    __syncthreads();  // staging + ssq visible

    // ---- GEMM1 (logits) + softmax over K=64 (in-register)
    {
      const int prow_ = wv * 16 + ll;
      const int swz = (2 * wv + (ll >> 3)) & 7;
      f32x4 lg[4];
#pragma unroll
      for (int kt = 0; kt < 4; ++kt) lg[kt] = (f32x4){0.f, 0.f, 0.f, 0.f};
#pragma unroll
      for (int ks = 0; ks < 4; ++ks) {
        bf16x8 bfrag = *(const bf16x8*)&xpd[prow_ * XPT + ((((ks << 2) | lq) ^ swz) << 3)];
#pragma unroll
        for (int kt = 0; kt < 4; ++kt) {
          bf16x8 afrag = *(const bf16x8*)&w_s[(kt * 16 + ll) * WT + ks * 32 + lq * 8];
          lg[kt] = __builtin_amdgcn_mfma_f32_16x16x32_bf16(afrag, bfrag, lg[kt], 0, 0, 0);
        }
      }
      float iv = 1.0f / fmaxf(sqrtf(red_s[prow_]), 1e-12f);
      float vals[16];
      float m = -1e30f;
#pragma unroll
      for (int kt = 0; kt < 4; ++kt)
#pragma unroll
        for (int r = 0; r < 4; ++r) {
          float v = lg[kt][r] * iv;
          vals[kt * 4 + r] = v;
          m = fmaxf(m, v);
        }
      m = fmaxf(m, __shfl_xor(m, 16));
      m = fmaxf(m, __shfl_xor(m, 32));
      float se = 0.f;
#pragma unroll
      for (int i = 0; i < 16; ++i) {
        float e = __expf(vals[i] - m);
        vals[i] = e;
        se += e;
      }
      se += __shfl_xor(se, 16);
      se += __shfl_xor(se, 32);
      float rinv = 1.0f / se;
      float r2 = rinv * iv;  // fold invn into sa for GEMM2
#pragma unroll
      for (int kt = 0; kt < 4; ++kt)
#pragma unroll
        for (int r = 0; r < 4; ++r) {
          float e = vals[kt * 4 + r];
          ssacc[kt * 4 + r] += e * rinv;
          sa_s[(kt * 16 + lq * 4 + r) * SAT + prow_] = f2bf(e * r2);
        }
    }
    __syncthreads();  // sa_s visible
    if (c + 1 < NCH && t < 64) red_s[t] = 0.f;  // re-zero ssq for next chunk

    // ---- GEMM2: acc[k-tile = wv][dt] += SA * X^T over this chunk
#pragma unroll
    for (int ks = 0; ks < 2; ++ks) {
      bf16x8 afrag = *(const bf16x8*)&sa_s[(wv * 16 + ll) * SAT + ks * 32 + lq * 8];
#pragma unroll
      for (int dt = 0; dt < 8; ++dt) {
        bf16x8 bfrag = *(const bf16x8*)&xdp[(dt * 16 + ll) * XDT + ks * 32 + lq * 8];
        acc[dt] = __builtin_amdgcn_mfma_f32_16x16x32_bf16(afrag, bfrag, acc[dt], 0, 0, 0);
      }
    }
  }

  // ---- flush agg partial slab (C-layout: k = 16wv+4lq+r, d = 16dt+ll)
  {
    float* base = pagg + (size_t)(n * BPN + sl) * (KK * DD);
#pragma unroll
    for (int dt = 0; dt < 8; ++dt)
#pragma unroll
      for (int r = 0; r < 4; ++r)
        base[(16 * wv + 4 * lq + r) * DD + dt * 16 + ll] = acc[dt][r];
  }
  // ---- flush ssum
#pragma unroll
  for (int i = 0; i < 16; ++i) {
    float s = ssacc[i];
    s += __shfl_xor(s, 1);
    s += __shfl_xor(s, 2);
    s += __shfl_xor(s, 4);
    s += __shfl_xor(s, 8);
    if (ll == 0) red_s[wv * 64 + (i >> 2) * 16 + lq * 4 + (i & 3)] = s;
  }
  __syncthreads();
  if (t < 64)
    pssum[(n * BPN + sl) * KK + t] =
        red_s[t] + red_s[64 + t] + red_s[128 + t] + red_s[192 + t];
}

// ---------------------------------------------------------------------------
// Epilogue 1 (512 blocks): reduce 15 slabs, vlad = agg - ssum*cent,
// intra-normalize per k, store to vtmp + per-block global-norm partial.
// ---------------------------------------------------------------------------
__global__ __launch_bounds__(256) void ep1_kernel(const float* __restrict__ pagg,
                                                  const float* __restrict__ pssum,
                                                  const float* __restrict__ cent,
                                                  float* __restrict__ vtmp,
                                                  float* __restrict__ gsum) {
  __shared__ float wsum[4];
  const int blk = blockIdx.x;
  const int n = blk >> 3, kg = blk & 7;
  const int t = threadIdx.x;
  const int kl = t >> 5, c32 = t & 31;  // k-row in block, 32 lanes per row
  const int k = kg * 8 + kl;
  const size_t off = (size_t)k * DD + c32 * 4;

  const float* base = pagg + (size_t)n * BPN * (KK * DD) + off;
  float4 a = {0.f, 0.f, 0.f, 0.f};
  for (int s = 0; s < BPN; ++s) {
    float4 v = *(const float4*)(base + (size_t)s * (KK * DD));
    a.x += v.x; a.y += v.y; a.z += v.z; a.w += v.w;
  }
  float sk = 0.f;
  for (int s = 0; s < BPN; ++s) sk += pssum[(n * BPN + s) * KK + k];

  float4 c4 = *(const float4*)(cent + off);
  float4 v;
  v.x = fmaf(-sk, c4.x, a.x);
  v.y = fmaf(-sk, c4.y, a.y);
  v.z = fmaf(-sk, c4.z, a.z);
  v.w = fmaf(-sk, c4.w, a.w);

  float pss = v.x * v.x + v.y * v.y + v.z * v.z + v.w * v.w;  // thread partial
  float ss = pss;
  ss += __shfl_xor(ss, 1);
  ss += __shfl_xor(ss, 2);
  ss += __shfl_xor(ss, 4);
  ss += __shfl_xor(ss, 8);
  ss += __shfl_xor(ss, 16);  // row total (32 lanes per k-row)
  float rinv = 1.0f / fmaxf(sqrtf(ss), 1e-12f);
  v.x *= rinv; v.y *= rinv; v.z *= rinv; v.w *= rinv;
  *(float4*)(vtmp + (size_t)n * (KK * DD) + off) = v;

  float gp = pss * rinv * rinv;  // post-norm partial for global L2
#pragma unroll
  for (int o = 1; o < 64; o <<= 1) gp += __shfl_xor(gp, o);
  if ((t & 63) == 0) wsum[t >> 6] = gp;
  __syncthreads();
  if (t == 0) gsum[blk] = wsum[0] + wsum[1] + wsum[2] + wsum[3];
}

// ---------------------------------------------------------------------------
// Epilogue 2 (64 blocks): global L2 normalize and store.
// ---------------------------------------------------------------------------
__global__ __launch_bounds__(256) void ep2_kernel(const float* __restrict__ vtmp,
                                                  const float* __restrict__ gsum,
                                                  float* __restrict__ out) {
  const int n = blockIdx.x, t = threadIdx.x;
  const float* gs = gsum + n * 8;
  float g = gs[0] + gs[1] + gs[2] + gs[3] + gs[4] + gs[5] + gs[6] + gs[7];
  float ginv = 1.0f / fmaxf(sqrtf(g), 1e-12f);
  const float4* vi = (const float4*)(vtmp + (size_t)n * (KK * DD));
  float4* vo = (float4*)(out + (size_t)n * (KK * DD));
#pragma unroll
  for (int it = 0; it < 8; ++it) {
    int idx = t + 256 * it;
    float4 f = vi[idx];
    f.x *= ginv; f.y *= ginv; f.z *= ginv; f.w *= ginv;
    vo[idx] = f;
  }
}

extern "C" void kernel_launch(void* const* d_in, const int* in_sizes, int n_in,
                              void* d_out, int out_size, void* d_ws, size_t ws_size,
                              hipStream_t stream) {
  const float* x      = (const float*)d_in[0];
  const float* conv_w = (const float*)d_in[1];
  const float* cent   = (const float*)d_in[2];
  float* out = (float*)d_out;
  float* ws  = (float*)d_ws;

  float* pagg  = ws;
  float* pssum = pagg + PAGG_SZ;
  float* vtmp  = pssum + PSSUM_SZ;
  float* gsum  = vtmp + VTMP_SZ;

  main_kernel<<<NN * BPN, 256, 0, stream>>>(x, conv_w, pagg, pssum);
  ep1_kernel<<<NN * 8, 256, 0, stream>>>(pagg, pssum, cent, vtmp, gsum);
  ep2_kernel<<<NN, 256, 0, stream>>>(vtmp, gsum, out);
}